// Round 10
// baseline (167.993 us; speedup 1.0000x reference)
//
#include <hip/hip_runtime.h>

#define NR 131072
#define DD 32
#define KK 64
#define BETA_C 10.0f
#define WROWS 256                    // rows per syrk worker
#define GRIDW 640                    // >= sum ceil(c_k/WROWS) <= 512+64 = 576
#define TRI(i, j) ((i) * ((i) + 1) / 2 + (j))
#define LSTR 40                      // LDS row stride in ushort (80 B: 16B-aligned, 2-way banks)

typedef __attribute__((ext_vector_type(8))) short short8;   // 8 bf16 (4 VGPR)
typedef __attribute__((ext_vector_type(4))) float float4e;  // MFMA acc

// ---------------------------------------------------------------------------
// ws layout (float-indexed), ws_size = 256 MiB (R6 counter evidence):
//   [0,64)        fill_g    [64,65) lossAcc
//   [128,192)     hist_g (int)      [192,260) segStart (int 65)
//   [320,384)     cursor (int)      [384,544) wk (uchar GRIDW)
//   [544,1184)    wbase (int)       [1184,1824) wcnt (int)
//   [1824,35616)  m2low_g (K x 528 tri)   [35616,37664) sums_g (K x 32)
//   [37664,70432) pred8 (uchar N)   [70432,+N*D) xsort (cluster-sorted x)
// memset zeroes [0,37664) floats; everything past is fully overwritten.
// ---------------------------------------------------------------------------

__device__ __forceinline__ unsigned short bf16_rne(float f) {
  const unsigned u = __float_as_uint(f);
  return (unsigned short)((u + 0x7FFFu + ((u >> 16) & 1u)) >> 16);
}
__device__ __forceinline__ float bf16_f(unsigned short h) {
  return __uint_as_float(((unsigned)h) << 16);
}

// phase 1 v6 (MFMA): block = 64 rows x 4 waves. Stage x rows and centers in
// LDS as split-bf16 (hi + residual-lo; ~2^-18 effective precision). Wave w
// computes its 16x64 slice of S = X C^T with 3 mfma_f32_16x16x32_bf16 per
// 16x16 tile (hh + hl + lh). d2 = xx - 2S + cc in fp32; per-row argmin
// (lexicographic = first-index ties) + softmax via 16-lane shuffle groups.
// Outputs identical in kind to R8: pred8, histS->hist_g, fillW->fill_g.
__global__ __launch_bounds__(256) void phase1_kernel(
    const float* __restrict__ x, const float* __restrict__ centers,
    float* __restrict__ fill_g, int* __restrict__ hist_g,
    unsigned char* __restrict__ pred_g) {
  __shared__ __align__(16) unsigned short xhS[64 * LSTR];
  __shared__ __align__(16) unsigned short xlS[64 * LSTR];
  __shared__ __align__(16) unsigned short chS[64 * LSTR];
  __shared__ __align__(16) unsigned short clS[64 * LSTR];
  __shared__ float xxS[64];
  __shared__ float cnS[64];
  __shared__ float fillW[4][KK];
  __shared__ int histS[KK];

  const int tid = threadIdx.x;
  const int lane = tid & 63;
  const int w = tid >> 6;
  if (tid < KK) histS[tid] = 0;

  const int r4 = tid >> 2;  // staged row 0..63 (4 threads per row)
  const int sg = tid & 3;   // 8-float segment within the row

  // ---- stage centers (hi/lo bf16 + ||c||^2) ----
  {
    const float* cp = centers + r4 * DD + sg * 8;
    const float4 a = *(const float4*)cp;
    const float4 bq = *(const float4*)(cp + 4);
    const float vv[8] = {a.x, a.y, a.z, a.w, bq.x, bq.y, bq.z, bq.w};
    unsigned short hs[8], ls[8];
    float cc = 0.f;
#pragma unroll
    for (int j = 0; j < 8; ++j) {
      hs[j] = bf16_rne(vv[j]);
      ls[j] = bf16_rne(vv[j] - bf16_f(hs[j]));  // residual (Sterbenz-exact)
      cc += vv[j] * vv[j];
    }
    cc += __shfl_xor(cc, 1, 64);
    cc += __shfl_xor(cc, 2, 64);
    if (sg == 0) cnS[r4] = cc;
    uint4 ph, pl;
    ph.x = hs[0] | (hs[1] << 16); ph.y = hs[2] | (hs[3] << 16);
    ph.z = hs[4] | (hs[5] << 16); ph.w = hs[6] | (hs[7] << 16);
    pl.x = ls[0] | (ls[1] << 16); pl.y = ls[2] | (ls[3] << 16);
    pl.z = ls[4] | (ls[5] << 16); pl.w = ls[6] | (ls[7] << 16);
    *(uint4*)&chS[r4 * LSTR + sg * 8] = ph;
    *(uint4*)&clS[r4 * LSTR + sg * 8] = pl;
  }
  // ---- stage x rows (hi/lo bf16 + ||x||^2) ----
  {
    const float* xp = x + ((size_t)blockIdx.x * 64 + r4) * DD + sg * 8;
    const float4 a = *(const float4*)xp;
    const float4 bq = *(const float4*)(xp + 4);
    const float vv[8] = {a.x, a.y, a.z, a.w, bq.x, bq.y, bq.z, bq.w};
    unsigned short hs[8], ls[8];
    float xx = 0.f;
#pragma unroll
    for (int j = 0; j < 8; ++j) {
      hs[j] = bf16_rne(vv[j]);
      ls[j] = bf16_rne(vv[j] - bf16_f(hs[j]));
      xx += vv[j] * vv[j];
    }
    xx += __shfl_xor(xx, 1, 64);
    xx += __shfl_xor(xx, 2, 64);
    if (sg == 0) xxS[r4] = xx;
    uint4 ph, pl;
    ph.x = hs[0] | (hs[1] << 16); ph.y = hs[2] | (hs[3] << 16);
    ph.z = hs[4] | (hs[5] << 16); ph.w = hs[6] | (hs[7] << 16);
    pl.x = ls[0] | (ls[1] << 16); pl.y = ls[2] | (ls[3] << 16);
    pl.z = ls[4] | (ls[5] << 16); pl.w = ls[6] | (ls[7] << 16);
    *(uint4*)&xhS[r4 * LSTR + sg * 8] = ph;
    *(uint4*)&xlS[r4 * LSTR + sg * 8] = pl;
  }
  __syncthreads();

  const int c = lane & 15;  // tile col / A-row selector
  const int q = lane >> 4;  // quad (k-octet / C row-group)

  // A fragments: A[m=lane&15][k=q*8+j]  (verified layout, m120)
  const short8 Ah = *(const short8*)&xhS[(w * 16 + c) * LSTR + q * 8];
  const short8 Al = *(const short8*)&xlS[(w * 16 + c) * LSTR + q * 8];

  float4e acc[4];
#pragma unroll
  for (int t = 0; t < 4; ++t) {
    // B fragments: B[k=q*8+j][n=lane&15] with C stored [cluster][dim]
    const short8 Bh = *(const short8*)&chS[(t * 16 + c) * LSTR + q * 8];
    const short8 Bl = *(const short8*)&clS[(t * 16 + c) * LSTR + q * 8];
    float4e a = {0.f, 0.f, 0.f, 0.f};
    a = __builtin_amdgcn_mfma_f32_16x16x32_bf16(Ah, Bh, a, 0, 0, 0);
    a = __builtin_amdgcn_mfma_f32_16x16x32_bf16(Ah, Bl, a, 0, 0, 0);
    a = __builtin_amdgcn_mfma_f32_16x16x32_bf16(Al, Bh, a, 0, 0, 0);
    acc[t] = a;
  }

  // d2[t][reg] for row = w*16 + q*4 + reg, col k = t*16 + c
  float d2v[4][4];
  float xxr[4];
#pragma unroll
  for (int r = 0; r < 4; ++r) xxr[r] = xxS[w * 16 + q * 4 + r];
#pragma unroll
  for (int t = 0; t < 4; ++t) {
    const float cn = cnS[t * 16 + c];
#pragma unroll
    for (int r = 0; r < 4; ++r)
      d2v[t][r] = xxr[r] - 2.0f * acc[t][r] + cn;
  }

  float pfill[4] = {0.f, 0.f, 0.f, 0.f};
#pragma unroll
  for (int r = 0; r < 4; ++r) {
    // argmin over this row's 64 d2: in-lane over t (k ascending, strict <),
    // then lexicographic 16-lane butterfly (first-index tie semantics).
    float b = d2v[0][r];
    int bi = 0 * 16 + c;
#pragma unroll
    for (int t = 1; t < 4; ++t)
      if (d2v[t][r] < b) { b = d2v[t][r]; bi = t * 16 + c; }
#pragma unroll
    for (int m = 1; m <= 8; m <<= 1) {
      const float bo = __shfl_xor(b, m, 64);
      const int bio = __shfl_xor(bi, m, 64);
      if (bo < b || (bo == b && bio < bi)) { b = bo; bi = bio; }
    }
    float e[4];
    float z = 0.f;
#pragma unroll
    for (int t = 0; t < 4; ++t) {
      e[t] = __expf(BETA_C * (b - d2v[t][r]));  // arg <= 0
      z += e[t];
    }
#pragma unroll
    for (int m = 1; m <= 8; m <<= 1) z += __shfl_xor(z, m, 64);
    const float invz = 1.0f / z;
#pragma unroll
    for (int t = 0; t < 4; ++t) pfill[t] += e[t] * invz;
    if (c == 0) {
      const int rowG = blockIdx.x * 64 + w * 16 + q * 4 + r;
      pred_g[rowG] = (unsigned char)bi;
      atomicAdd(&histS[bi], 1);
    }
  }

  // fill: sum over the wave's 16 rows (quads) -> fillW[w][k]
#pragma unroll
  for (int t = 0; t < 4; ++t) {
    float s = pfill[t];
    s += __shfl_xor(s, 16, 64);
    s += __shfl_xor(s, 32, 64);
    if (lane < 16) fillW[w][t * 16 + lane] = s;
  }
  __syncthreads();
  if (tid < KK) {
    atomicAdd(&fill_g[tid],
              fillW[0][tid] + fillW[1][tid] + fillW[2][tid] + fillW[3][tid]);
    if (histS[tid]) atomicAdd(&hist_g[tid], histS[tid]);
  }
}

// planner v2 (R8 verbatim, validated): wave-shuffle scans, worker table.
__global__ void planner_kernel(const int* __restrict__ hist_g,
                               int* __restrict__ segStart,
                               int* __restrict__ cursor,
                               unsigned char* __restrict__ wk,
                               int* __restrict__ wbase,
                               int* __restrict__ wcnt) {
  const int t = threadIdx.x;  // 64 threads, one wave
  const int c = hist_g[t];

  int inc = c;
#pragma unroll
  for (int off = 1; off < 64; off <<= 1) {
    const int v = __shfl_up(inc, off, 64);
    if (t >= off) inc += v;
  }
  const int seg = inc - c;
  segStart[t] = seg;
  cursor[t] = seg;
  if (t == 63) segStart[KK] = inc;

  const int nw = (c + WROWS - 1) / WROWS;
  int winc = nw;
#pragma unroll
  for (int off = 1; off < 64; off <<= 1) {
    const int v = __shfl_up(winc, off, 64);
    if (t >= off) winc += v;
  }
  const int woff = winc - nw;
  const int wtot = __shfl(winc, 63, 64);

  for (int wi = 0; wi < nw; ++wi) {
    wk[woff + wi] = (unsigned char)t;
    wbase[woff + wi] = seg + wi * WROWS;
    wcnt[woff + wi] = min(WROWS, c - wi * WROWS);
  }
  for (int w = wtot + t; w < GRIDW; w += 64) wk[w] = 255;
}

// scatter (R8 verbatim, validated): counting-sort x into xsort.
__global__ __launch_bounds__(256) void scatter_kernel(
    const float* __restrict__ x, const unsigned char* __restrict__ pred_g,
    int* __restrict__ cursor, float* __restrict__ xsort) {
  __shared__ int histS[KK];
  __shared__ int baseS[KK];
  __shared__ int slotS[256];

  const int tid = threadIdx.x;
  if (tid < KK) histS[tid] = 0;
  __syncthreads();

  const int row = blockIdx.x * 256 + tid;
  const int bi = pred_g[row];
  const int rank = atomicAdd(&histS[bi], 1);
  __syncthreads();
  if (tid < KK) {
    const int hh = histS[tid];
    baseS[tid] = hh ? atomicAdd(&cursor[tid], hh) : 0;
  }
  __syncthreads();
  slotS[tid] = baseS[bi] + rank;
  __syncthreads();

  const float4* xin = (const float4*)x + (size_t)blockIdx.x * 2048;
  float4* xo = (float4*)xsort;
#pragma unroll
  for (int j = 0; j < 8; ++j) {
    const int f = tid + 256 * j;
    const int rl = f >> 3;
    const int pt = f & 7;
    xo[(size_t)slotS[rl] * 8 + pt] = xin[f];  // reads perfectly coalesced
  }
}

// syrk (R8 verbatim, validated).
__global__ __launch_bounds__(256) void syrk_kernel(
    const float* __restrict__ xsort, const unsigned char* __restrict__ wk,
    const int* __restrict__ wbase, const int* __restrict__ wcnt,
    float* __restrict__ m2low_g, float* __restrict__ sums_g) {
  __shared__ float xsT[DD][68];

  const int b = blockIdx.x;
  const int k = wk[b];
  if (k == 255) return;
  const int tid = threadIdx.x;
  const int base = wbase[b];
  const int total = wcnt[b];

  const int ti = tid >> 4, tj = tid & 15;
  const int i0 = ti, i1 = ti + 16, j0 = tj, j1 = tj + 16;
  float c00 = 0.f, c10 = 0.f, c11 = 0.f, sd0 = 0.f, sd1 = 0.f;

  for (int off = 0; off < total; off += 64) {
    const int cnt = min(64, total - off);
    const int cnt4 = (cnt + 3) & ~3;
    __syncthreads();
    const float* src = xsort + (size_t)(base + off) * DD;
    for (int e = tid; e < cnt * DD; e += 256)
      xsT[e & 31][e >> 5] = src[e];  // fully coalesced
    for (int e = cnt * DD + tid; e < cnt4 * DD; e += 256)
      xsT[e & 31][e >> 5] = 0.f;
    __syncthreads();
    for (int g = 0; g < (cnt4 >> 2); ++g) {
      const float4 A0 = *(const float4*)&xsT[i0][4 * g];
      const float4 A1 = *(const float4*)&xsT[i1][4 * g];
      const float4 B0 = *(const float4*)&xsT[j0][4 * g];
      const float4 B1 = *(const float4*)&xsT[j1][4 * g];
      c00 += A0.x * B0.x + A0.y * B0.y + A0.z * B0.z + A0.w * B0.w;
      c10 += A1.x * B0.x + A1.y * B0.y + A1.z * B0.z + A1.w * B0.w;
      c11 += A1.x * B1.x + A1.y * B1.y + A1.z * B1.z + A1.w * B1.w;
      if (tj == 0) {
        sd0 += A0.x + A0.y + A0.z + A0.w;
        sd1 += A1.x + A1.y + A1.z + A1.w;
      }
    }
  }

  float* m2k = m2low_g + k * 528;
  atomicAdd(&m2k[TRI(i1, j0)], c10);
  if (tj <= ti) {
    atomicAdd(&m2k[TRI(i0, j0)], c00);
    atomicAdd(&m2k[TRI(i1, j1)], c11);
  }
  if (tj == 0) {
    atomicAdd(&sums_g[k * DD + i0], sd0);
    atomicAdd(&sums_g[k * DD + i1], sd1);
  }
}

// finalize A (R8 verbatim, validated): one block per cluster.
__global__ __launch_bounds__(256) void finalizeA_kernel(
    const float* __restrict__ fill_g, const int* __restrict__ hist_g,
    const float* __restrict__ sums_g, const float* __restrict__ m2low_g,
    const float* __restrict__ ft, const float* __restrict__ mt,
    const float* __restrict__ ct, float* __restrict__ lossAcc) {
  __shared__ float meanS[DD];
  __shared__ float wred[4];
  const int t = threadIdx.x;
  const int k = blockIdx.x;

  const float inv = 1.0f / fmaxf((float)hist_g[k], 1.0f);
  if (t < DD) meanS[t] = sums_g[k * DD + t] * inv;
  __syncthreads();

  float acc = 0.f;
  if (t < DD) {
    const float d = meanS[t] - mt[k * DD + t];
    acc += d * d * (1.0f / (KK * DD));
  }
  if (t == 0) {
    const float f = fill_g[k] * (1.0f / (float)NR) - ft[k];
    acc += f * f * (1.0f / KK);
  }
  const float* m2k = m2low_g + k * 528;
  const float* ctk = ct + k * (DD * DD);
#pragma unroll
  for (int u = 0; u < 4; ++u) {
    const int e = t + 256 * u;
    const int i = e >> 5, j = e & 31;
    const int idx = (i >= j) ? TRI(i, j) : TRI(j, i);
    const float cov = m2k[idx] * inv - meanS[i] * meanS[j];
    const float d = cov - ctk[e];
    acc += d * d * (1.0f / (KK * DD * DD));
  }

  acc += __shfl_xor(acc, 32, 64);
  acc += __shfl_xor(acc, 16, 64);
  acc += __shfl_xor(acc, 8, 64);
  acc += __shfl_xor(acc, 4, 64);
  acc += __shfl_xor(acc, 2, 64);
  acc += __shfl_xor(acc, 1, 64);
  if ((t & 63) == 0) wred[t >> 6] = acc;
  __syncthreads();
  if (t == 0) atomicAdd(lossAcc, wred[0] + wred[1] + wred[2] + wred[3]);
}

__global__ void finalizeB_kernel(const float* __restrict__ lossAcc,
                                 float* __restrict__ out) {
  if (threadIdx.x == 0) out[0] = lossAcc[0];
}

extern "C" void kernel_launch(void* const* d_in, const int* in_sizes, int n_in,
                              void* d_out, int out_size, void* d_ws,
                              size_t ws_size, hipStream_t stream) {
  (void)in_sizes; (void)n_in; (void)out_size; (void)ws_size;
  const float* x = (const float*)d_in[0];
  const float* centers = (const float*)d_in[1];
  const float* ft = (const float*)d_in[2];
  const float* mt = (const float*)d_in[3];
  const float* ct = (const float*)d_in[4];
  float* out = (float*)d_out;

  float* ws = (float*)d_ws;
  float* fill_g = ws;                                   // 64
  float* lossAcc = ws + 64;                             // 1
  int* hist_g = (int*)(ws + 128);                       // 64
  int* segStart = (int*)(ws + 192);                     // 65
  int* cursor = (int*)(ws + 320);                       // 64
  unsigned char* wk = (unsigned char*)(ws + 384);       // GRIDW bytes
  int* wbase = (int*)(ws + 544);                        // GRIDW
  int* wcnt = (int*)(ws + 1184);                        // GRIDW
  float* m2low_g = ws + 1824;                           // 33792
  float* sums_g = ws + 35616;                           // 2048
  unsigned char* pred8 = (unsigned char*)(ws + 37664);  // N bytes
  float* xsort = ws + 70432;                            // N*D floats (16 MB)

  hipMemsetAsync(d_ws, 0, (size_t)37664 * sizeof(float), stream);

  phase1_kernel<<<NR / 64, 256, 0, stream>>>(x, centers, fill_g, hist_g,
                                             pred8);
  planner_kernel<<<1, 64, 0, stream>>>(hist_g, segStart, cursor, wk, wbase,
                                       wcnt);
  scatter_kernel<<<NR / 256, 256, 0, stream>>>(x, pred8, cursor, xsort);
  syrk_kernel<<<GRIDW, 256, 0, stream>>>(xsort, wk, wbase, wcnt, m2low_g,
                                         sums_g);
  finalizeA_kernel<<<KK, 256, 0, stream>>>(fill_g, hist_g, sums_g, m2low_g, ft,
                                           mt, ct, lossAcc);
  finalizeB_kernel<<<1, 64, 0, stream>>>(lossAcc, out);
}

// Round 11
// 155.490 us; speedup vs baseline: 1.0804x; 1.0804x over previous
//
#include <hip/hip_runtime.h>

#define NR 131072
#define DD 32
#define KK 64
#define BETA_C 10.0f
#define NB1 (NR / 256)  // 512 phase1 blocks
#define WROWS 256       // rows per syrk worker
#define GRIDW 640       // >= sum ceil(c_k/WROWS) <= 512+64 = 576
#define TRI(i, j) ((i) * ((i) + 1) / 2 + (j))

// ---------------------------------------------------------------------------
// ws layout (float-indexed), ws_size = 256 MiB:
//   [0,64)        fill_g          [64,65) lossAcc
//   [66,67)       done1 (int)     [67,68) done2 (int)
//   [128,192)     hist_g (int)
//   [192,33984)   m2low_g (K x 528 tri)
//   [33984,36032) sums_g (K x 32)          <-- memset covers [0,36032)
//   [36160,36224) cursor (int 64)
//   [36224,36384) wk (uchar GRIDW)
//   [36384,37024) wbase (int GRIDW)
//   [37024,37664) wcnt (int GRIDW)
//   [37664,70432) pred8 (uchar N)
//   [70432,...)   xsort (N*D floats)
// planner outputs / pred8 / xsort are fully overwritten each launch.
// ---------------------------------------------------------------------------

// phase 1 (R8-verbatim core, validated) + last-block planner fold.
__global__ __launch_bounds__(256) void phase1_kernel(
    const float* __restrict__ x, const float* __restrict__ centers,
    float* __restrict__ fill_g, int* __restrict__ hist_g,
    unsigned char* __restrict__ pred_g, int* __restrict__ done1,
    int* __restrict__ cursor, unsigned char* __restrict__ wk,
    int* __restrict__ wbase, int* __restrict__ wcnt) {
  __shared__ float cnS[KK];
  __shared__ float fillW[4][KK];
  __shared__ int histS[KK];
  __shared__ int lastS;

  const int tid = threadIdx.x;
  const int lane = tid & 63;
  const int wid = tid >> 6;

  if (tid < KK) {
    float s = 0.f;
    const float* cp = centers + tid * DD;
#pragma unroll
    for (int j = 0; j < DD; ++j) s += cp[j] * cp[j];
    cnS[tid] = s;
    histS[tid] = 0;
  }
  __syncthreads();

  const int row = blockIdx.x * 256 + tid;  // grid == NR/256 exactly

  float xr[DD];
  const float4* xp = (const float4*)(x + (size_t)row * DD);
#pragma unroll
  for (int j = 0; j < 8; ++j) {
    const float4 v = xp[j];
    xr[4 * j + 0] = v.x;
    xr[4 * j + 1] = v.y;
    xr[4 * j + 2] = v.z;
    xr[4 * j + 3] = v.w;
  }
  float xx = 0.f;
#pragma unroll
  for (int j = 0; j < DD; ++j) xx += xr[j] * xr[j];

  float pv[KK];
  float best = 3.4e38f;
  int bi = 0;
#pragma unroll
  for (int k = 0; k < KK; ++k) {
    float dot = 0.f;
#pragma unroll
    for (int j = 0; j < DD; ++j)
      dot += xr[j] * centers[k * DD + j];  // uniform addr -> s_load (K$)
    const float d2 = xx - 2.0f * dot + cnS[k];
    pv[k] = d2;
    if (d2 < best) { best = d2; bi = k; }  // strict < == first-index ties
  }
  pred_g[row] = (unsigned char)bi;
  atomicAdd(&histS[bi], 1);

  float ssum = 0.f;
#pragma unroll
  for (int k = 0; k < KK; ++k) {
    const float e = __expf(BETA_C * (best - pv[k]));
    pv[k] = e;
    ssum += e;
  }
  const float inv = 1.0f / ssum;
#pragma unroll
  for (int k = 0; k < KK; ++k) pv[k] *= inv;

#pragma unroll
  for (int m = 32; m >= 1; m >>= 1) {
    const bool hi = (lane & m) != 0;
#pragma unroll
    for (int i = 0; i < m; ++i) {
      const float send = hi ? pv[i] : pv[i + m];
      const float recv = __shfl_xor(send, m, 64);
      const float keep = hi ? pv[i + m] : pv[i];
      pv[i] = keep + recv;
    }
  }
  fillW[wid][lane] = pv[0];
  __syncthreads();
  if (tid < KK) {
    atomicAdd(&fill_g[tid],
              fillW[0][tid] + fillW[1][tid] + fillW[2][tid] + fillW[3][tid]);
    if (histS[tid]) atomicAdd(&hist_g[tid], histS[tid]);
  }

  // ---- last-block planner fold (replaces the planner kernel node) ----
  __threadfence();  // each thread orders its atomics before the ticket
  __syncthreads();
  if (tid == 0) lastS = (atomicAdd(done1, 1) == NB1 - 1);
  __syncthreads();
  if (lastS && tid < 64) {
    __threadfence();
    const int t = tid;  // one wave == the R8 planner's 64 threads
    const int c = atomicAdd(&hist_g[t], 0);  // coherent read of final count

    int inc = c;
#pragma unroll
    for (int off = 1; off < 64; off <<= 1) {
      const int v = __shfl_up(inc, off, 64);
      if (t >= off) inc += v;
    }
    const int seg = inc - c;
    cursor[t] = seg;

    const int nw = (c + WROWS - 1) / WROWS;
    int winc = nw;
#pragma unroll
    for (int off = 1; off < 64; off <<= 1) {
      const int v = __shfl_up(winc, off, 64);
      if (t >= off) winc += v;
    }
    const int woff = winc - nw;
    const int wtot = __shfl(winc, 63, 64);

    for (int wi = 0; wi < nw; ++wi) {
      wk[woff + wi] = (unsigned char)t;
      wbase[woff + wi] = seg + wi * WROWS;
      wcnt[woff + wi] = min(WROWS, c - wi * WROWS);
    }
    for (int w = wtot + t; w < GRIDW; w += 64) wk[w] = 255;
  }
}

// scatter (R8 verbatim, validated): counting-sort x into xsort.
__global__ __launch_bounds__(256) void scatter_kernel(
    const float* __restrict__ x, const unsigned char* __restrict__ pred_g,
    int* __restrict__ cursor, float* __restrict__ xsort) {
  __shared__ int histS[KK];
  __shared__ int baseS[KK];
  __shared__ int slotS[256];

  const int tid = threadIdx.x;
  if (tid < KK) histS[tid] = 0;
  __syncthreads();

  const int row = blockIdx.x * 256 + tid;
  const int bi = pred_g[row];
  const int rank = atomicAdd(&histS[bi], 1);
  __syncthreads();
  if (tid < KK) {
    const int hh = histS[tid];
    baseS[tid] = hh ? atomicAdd(&cursor[tid], hh) : 0;
  }
  __syncthreads();
  slotS[tid] = baseS[bi] + rank;
  __syncthreads();

  const float4* xin = (const float4*)x + (size_t)blockIdx.x * 2048;
  float4* xo = (float4*)xsort;
#pragma unroll
  for (int j = 0; j < 8; ++j) {
    const int f = tid + 256 * j;
    const int rl = f >> 3;
    const int pt = f & 7;
    xo[(size_t)slotS[rl] * 8 + pt] = xin[f];  // reads perfectly coalesced
  }
}

// syrk (R8 verbatim, validated).
__global__ __launch_bounds__(256) void syrk_kernel(
    const float* __restrict__ xsort, const unsigned char* __restrict__ wk,
    const int* __restrict__ wbase, const int* __restrict__ wcnt,
    float* __restrict__ m2low_g, float* __restrict__ sums_g) {
  __shared__ float xsT[DD][68];

  const int b = blockIdx.x;
  const int k = wk[b];
  if (k == 255) return;
  const int tid = threadIdx.x;
  const int base = wbase[b];
  const int total = wcnt[b];

  const int ti = tid >> 4, tj = tid & 15;
  const int i0 = ti, i1 = ti + 16, j0 = tj, j1 = tj + 16;
  float c00 = 0.f, c10 = 0.f, c11 = 0.f, sd0 = 0.f, sd1 = 0.f;

  for (int off = 0; off < total; off += 64) {
    const int cnt = min(64, total - off);
    const int cnt4 = (cnt + 3) & ~3;
    __syncthreads();
    const float* src = xsort + (size_t)(base + off) * DD;
    for (int e = tid; e < cnt * DD; e += 256)
      xsT[e & 31][e >> 5] = src[e];  // fully coalesced
    for (int e = cnt * DD + tid; e < cnt4 * DD; e += 256)
      xsT[e & 31][e >> 5] = 0.f;
    __syncthreads();
    for (int g = 0; g < (cnt4 >> 2); ++g) {
      const float4 A0 = *(const float4*)&xsT[i0][4 * g];
      const float4 A1 = *(const float4*)&xsT[i1][4 * g];
      const float4 B0 = *(const float4*)&xsT[j0][4 * g];
      const float4 B1 = *(const float4*)&xsT[j1][4 * g];
      c00 += A0.x * B0.x + A0.y * B0.y + A0.z * B0.z + A0.w * B0.w;
      c10 += A1.x * B0.x + A1.y * B0.y + A1.z * B0.z + A1.w * B0.w;
      c11 += A1.x * B1.x + A1.y * B1.y + A1.z * B1.z + A1.w * B1.w;
      if (tj == 0) {
        sd0 += A0.x + A0.y + A0.z + A0.w;
        sd1 += A1.x + A1.y + A1.z + A1.w;
      }
    }
  }

  float* m2k = m2low_g + k * 528;
  atomicAdd(&m2k[TRI(i1, j0)], c10);
  if (tj <= ti) {
    atomicAdd(&m2k[TRI(i0, j0)], c00);
    atomicAdd(&m2k[TRI(i1, j1)], c11);
  }
  if (tj == 0) {
    atomicAdd(&sums_g[k * DD + i0], sd0);
    atomicAdd(&sums_g[k * DD + i1], sd1);
  }
}

// finalize (R8-verbatim math, validated) + last-block out-write fold.
__global__ __launch_bounds__(256) void finalizeA_kernel(
    const float* __restrict__ fill_g, const int* __restrict__ hist_g,
    const float* __restrict__ sums_g, const float* __restrict__ m2low_g,
    const float* __restrict__ ft, const float* __restrict__ mt,
    const float* __restrict__ ct, float* __restrict__ lossAcc,
    int* __restrict__ done2, float* __restrict__ out) {
  __shared__ float meanS[DD];
  __shared__ float wred[4];
  const int t = threadIdx.x;
  const int k = blockIdx.x;

  const float inv = 1.0f / fmaxf((float)hist_g[k], 1.0f);
  if (t < DD) meanS[t] = sums_g[k * DD + t] * inv;
  __syncthreads();

  float acc = 0.f;
  if (t < DD) {
    const float d = meanS[t] - mt[k * DD + t];
    acc += d * d * (1.0f / (KK * DD));
  }
  if (t == 0) {
    const float f = fill_g[k] * (1.0f / (float)NR) - ft[k];
    acc += f * f * (1.0f / KK);
  }
  const float* m2k = m2low_g + k * 528;
  const float* ctk = ct + k * (DD * DD);
#pragma unroll
  for (int u = 0; u < 4; ++u) {
    const int e = t + 256 * u;
    const int i = e >> 5, j = e & 31;
    const int idx = (i >= j) ? TRI(i, j) : TRI(j, i);
    const float cov = m2k[idx] * inv - meanS[i] * meanS[j];
    const float d = cov - ctk[e];
    acc += d * d * (1.0f / (KK * DD * DD));
  }

  acc += __shfl_xor(acc, 32, 64);
  acc += __shfl_xor(acc, 16, 64);
  acc += __shfl_xor(acc, 8, 64);
  acc += __shfl_xor(acc, 4, 64);
  acc += __shfl_xor(acc, 2, 64);
  acc += __shfl_xor(acc, 1, 64);
  if ((t & 63) == 0) wred[t >> 6] = acc;
  __syncthreads();
  if (t == 0) {
    atomicAdd(lossAcc, wred[0] + wred[1] + wred[2] + wred[3]);
    __threadfence();
    if (atomicAdd(done2, 1) == KK - 1) {  // last block: emit the scalar
      __threadfence();
      out[0] = atomicAdd(lossAcc, 0.0f);  // returns the completed sum
    }
  }
}

extern "C" void kernel_launch(void* const* d_in, const int* in_sizes, int n_in,
                              void* d_out, int out_size, void* d_ws,
                              size_t ws_size, hipStream_t stream) {
  (void)in_sizes; (void)n_in; (void)out_size; (void)ws_size;
  const float* x = (const float*)d_in[0];
  const float* centers = (const float*)d_in[1];
  const float* ft = (const float*)d_in[2];
  const float* mt = (const float*)d_in[3];
  const float* ct = (const float*)d_in[4];
  float* out = (float*)d_out;

  float* ws = (float*)d_ws;
  float* fill_g = ws;                                   // 64
  float* lossAcc = ws + 64;                             // 1
  int* done1 = (int*)(ws + 66);                         // 1
  int* done2 = (int*)(ws + 67);                         // 1
  int* hist_g = (int*)(ws + 128);                       // 64
  float* m2low_g = ws + 192;                            // 33792
  float* sums_g = ws + 33984;                           // 2048 -> 36032
  int* cursor = (int*)(ws + 36160);                     // 64
  unsigned char* wk = (unsigned char*)(ws + 36224);     // GRIDW bytes
  int* wbase = (int*)(ws + 36384);                      // GRIDW
  int* wcnt = (int*)(ws + 37024);                       // GRIDW
  unsigned char* pred8 = (unsigned char*)(ws + 37664);  // N bytes
  float* xsort = ws + 70432;                            // N*D floats (16 MB)

  // zero fill/lossAcc/tickets/hist/m2low/sums in one node
  hipMemsetAsync(d_ws, 0, (size_t)36032 * sizeof(float), stream);

  phase1_kernel<<<NB1, 256, 0, stream>>>(x, centers, fill_g, hist_g, pred8,
                                         done1, cursor, wk, wbase, wcnt);
  scatter_kernel<<<NR / 256, 256, 0, stream>>>(x, pred8, cursor, xsort);
  syrk_kernel<<<GRIDW, 256, 0, stream>>>(xsort, wk, wbase, wcnt, m2low_g,
                                         sums_g);
  finalizeA_kernel<<<KK, 256, 0, stream>>>(fill_g, hist_g, sums_g, m2low_g, ft,
                                           mt, ct, lossAcc, done2, out);
}

// Round 12
// 138.509 us; speedup vs baseline: 1.2129x; 1.1226x over previous
//
#include <hip/hip_runtime.h>

#define NR 131072
#define DD 32
#define KK 64
#define BETA_C 10.0f
#define WROWS 256                    // rows per syrk worker
#define GRIDW 640                    // >= sum ceil(c_k/WROWS) <= 512+64 = 576
#define TRI(i, j) ((i) * ((i) + 1) / 2 + (j))

// ---------------------------------------------------------------------------
// ws layout (float-indexed), ws_size = 256 MiB (R6 counter evidence):
//   [0,64)        fill_g    [64,65) lossAcc
//   [128,192)     hist_g (int)      [192,260) segStart (int 65)
//   [320,384)     cursor (int)      [384,544) wk (uchar GRIDW)
//   [544,1184)    wbase (int)       [1184,1824) wcnt (int)
//   [1824,35616)  m2low_g (K x 528 tri)   [35616,37664) sums_g (K x 32)
//   [37664,70432) pred8 (uchar N)   [70432,+N*D) xsort (cluster-sorted x)
// memset zeroes [0,37664) floats; everything past is fully overwritten.
// ---------------------------------------------------------------------------

__device__ __forceinline__ float lane_bcast(float v, int k) {
  return __int_as_float(__builtin_amdgcn_readlane(__float_as_int(v), k));
}

// phase 1 v7: centers delivered via VGPR + v_readlane broadcast (zero memory
// latency, zero LDS pipe). Each lane loads center row `lane` into cr[32]
// once; per (k,j) the value comes from v_readlane -> SGPR -> v_fma v,s,v,v.
// d2/argmin/softmax expressions identical to R8 (bit-identical outputs).
__global__ __launch_bounds__(256) void phase1_kernel(
    const float* __restrict__ x, const float* __restrict__ centers,
    float* __restrict__ fill_g, int* __restrict__ hist_g,
    unsigned char* __restrict__ pred_g) {
  __shared__ float fillW[4][KK];
  __shared__ int histS[KK];

  const int tid = threadIdx.x;
  const int lane = tid & 63;
  const int wid = tid >> 6;

  if (tid < KK) histS[tid] = 0;
  __syncthreads();

  const int row = blockIdx.x * 256 + tid;  // grid == NR/256 exactly

  float xr[DD];  // row in VGPRs, compile-time indexed
  const float4* xp = (const float4*)(x + (size_t)row * DD);
#pragma unroll
  for (int j = 0; j < 8; ++j) {
    const float4 v = xp[j];
    xr[4 * j + 0] = v.x;
    xr[4 * j + 1] = v.y;
    xr[4 * j + 2] = v.z;
    xr[4 * j + 3] = v.w;
  }
  float xx = 0.f;
#pragma unroll
  for (int j = 0; j < DD; ++j) xx += xr[j] * xr[j];

  // lane l holds center row l (8 KB per wave, coalesced, loaded once)
  float cr[DD];
  const float4* cp = (const float4*)(centers + (size_t)lane * DD);
#pragma unroll
  for (int j = 0; j < 8; ++j) {
    const float4 v = cp[j];
    cr[4 * j + 0] = v.x;
    cr[4 * j + 1] = v.y;
    cr[4 * j + 2] = v.z;
    cr[4 * j + 3] = v.w;
  }
  float cc = 0.f;  // ||c_lane||^2, same j-ascending order as R8's cnS
#pragma unroll
  for (int j = 0; j < DD; ++j) cc += cr[j] * cr[j];

  float pv[KK];  // d2, then p; fully unrolled -> VGPRs
  float best = 3.4e38f;
  int bi = 0;
#pragma unroll
  for (int k = 0; k < KK; ++k) {
    float dot = 0.f;
#pragma unroll
    for (int j = 0; j < DD; ++j)
      dot += xr[j] * lane_bcast(cr[j], k);  // v_readlane -> s, v_fma v,s,v,v
    const float cn = lane_bcast(cc, k);
    const float d2 = xx - 2.0f * dot + cn;  // same formula/order as R8
    pv[k] = d2;
    if (d2 < best) { best = d2; bi = k; }  // strict < == first-index ties
  }
  pred_g[row] = (unsigned char)bi;
  atomicAdd(&histS[bi], 1);

  float ssum = 0.f;
#pragma unroll
  for (int k = 0; k < KK; ++k) {
    const float e = __expf(BETA_C * (best - pv[k]));  // arg <= 0
    pv[k] = e;
    ssum += e;
  }
  const float inv = 1.0f / ssum;
#pragma unroll
  for (int k = 0; k < KK; ++k) pv[k] *= inv;

  // 63-shuffle recursive-halving transpose-reduce (R8-validated)
#pragma unroll
  for (int m = 32; m >= 1; m >>= 1) {
    const bool hi = (lane & m) != 0;
#pragma unroll
    for (int i = 0; i < m; ++i) {
      const float send = hi ? pv[i] : pv[i + m];
      const float recv = __shfl_xor(send, m, 64);
      const float keep = hi ? pv[i + m] : pv[i];
      pv[i] = keep + recv;
    }
  }
  fillW[wid][lane] = pv[0];
  __syncthreads();
  if (tid < KK) {
    atomicAdd(&fill_g[tid],
              fillW[0][tid] + fillW[1][tid] + fillW[2][tid] + fillW[3][tid]);
    if (histS[tid]) atomicAdd(&hist_g[tid], histS[tid]);
  }
}

// planner v2 (R8 verbatim, validated): wave-shuffle scans, worker table.
__global__ void planner_kernel(const int* __restrict__ hist_g,
                               int* __restrict__ segStart,
                               int* __restrict__ cursor,
                               unsigned char* __restrict__ wk,
                               int* __restrict__ wbase,
                               int* __restrict__ wcnt) {
  const int t = threadIdx.x;  // 64 threads, one wave
  const int c = hist_g[t];

  int inc = c;
#pragma unroll
  for (int off = 1; off < 64; off <<= 1) {
    const int v = __shfl_up(inc, off, 64);
    if (t >= off) inc += v;
  }
  const int seg = inc - c;
  segStart[t] = seg;
  cursor[t] = seg;
  if (t == 63) segStart[KK] = inc;

  const int nw = (c + WROWS - 1) / WROWS;
  int winc = nw;
#pragma unroll
  for (int off = 1; off < 64; off <<= 1) {
    const int v = __shfl_up(winc, off, 64);
    if (t >= off) winc += v;
  }
  const int woff = winc - nw;
  const int wtot = __shfl(winc, 63, 64);

  for (int wi = 0; wi < nw; ++wi) {
    wk[woff + wi] = (unsigned char)t;
    wbase[woff + wi] = seg + wi * WROWS;
    wcnt[woff + wi] = min(WROWS, c - wi * WROWS);
  }
  for (int w = wtot + t; w < GRIDW; w += 64) wk[w] = 255;
}

// scatter (R8 verbatim, validated): counting-sort x into xsort.
__global__ __launch_bounds__(256) void scatter_kernel(
    const float* __restrict__ x, const unsigned char* __restrict__ pred_g,
    int* __restrict__ cursor, float* __restrict__ xsort) {
  __shared__ int histS[KK];
  __shared__ int baseS[KK];
  __shared__ int slotS[256];

  const int tid = threadIdx.x;
  if (tid < KK) histS[tid] = 0;
  __syncthreads();

  const int row = blockIdx.x * 256 + tid;
  const int bi = pred_g[row];
  const int rank = atomicAdd(&histS[bi], 1);
  __syncthreads();
  if (tid < KK) {
    const int hh = histS[tid];
    baseS[tid] = hh ? atomicAdd(&cursor[tid], hh) : 0;
  }
  __syncthreads();
  slotS[tid] = baseS[bi] + rank;
  __syncthreads();

  const float4* xin = (const float4*)x + (size_t)blockIdx.x * 2048;
  float4* xo = (float4*)xsort;
#pragma unroll
  for (int j = 0; j < 8; ++j) {
    const int f = tid + 256 * j;
    const int rl = f >> 3;
    const int pt = f & 7;
    xo[(size_t)slotS[rl] * 8 + pt] = xin[f];  // reads perfectly coalesced
  }
}

// syrk (R8 verbatim, validated).
__global__ __launch_bounds__(256) void syrk_kernel(
    const float* __restrict__ xsort, const unsigned char* __restrict__ wk,
    const int* __restrict__ wbase, const int* __restrict__ wcnt,
    float* __restrict__ m2low_g, float* __restrict__ sums_g) {
  __shared__ float xsT[DD][68];

  const int b = blockIdx.x;
  const int k = wk[b];
  if (k == 255) return;
  const int tid = threadIdx.x;
  const int base = wbase[b];
  const int total = wcnt[b];

  const int ti = tid >> 4, tj = tid & 15;
  const int i0 = ti, i1 = ti + 16, j0 = tj, j1 = tj + 16;
  float c00 = 0.f, c10 = 0.f, c11 = 0.f, sd0 = 0.f, sd1 = 0.f;

  for (int off = 0; off < total; off += 64) {
    const int cnt = min(64, total - off);
    const int cnt4 = (cnt + 3) & ~3;
    __syncthreads();
    const float* src = xsort + (size_t)(base + off) * DD;
    for (int e = tid; e < cnt * DD; e += 256)
      xsT[e & 31][e >> 5] = src[e];  // fully coalesced
    for (int e = cnt * DD + tid; e < cnt4 * DD; e += 256)
      xsT[e & 31][e >> 5] = 0.f;
    __syncthreads();
    for (int g = 0; g < (cnt4 >> 2); ++g) {
      const float4 A0 = *(const float4*)&xsT[i0][4 * g];
      const float4 A1 = *(const float4*)&xsT[i1][4 * g];
      const float4 B0 = *(const float4*)&xsT[j0][4 * g];
      const float4 B1 = *(const float4*)&xsT[j1][4 * g];
      c00 += A0.x * B0.x + A0.y * B0.y + A0.z * B0.z + A0.w * B0.w;
      c10 += A1.x * B0.x + A1.y * B0.y + A1.z * B0.z + A1.w * B0.w;
      c11 += A1.x * B1.x + A1.y * B1.y + A1.z * B1.z + A1.w * B1.w;
      if (tj == 0) {
        sd0 += A0.x + A0.y + A0.z + A0.w;
        sd1 += A1.x + A1.y + A1.z + A1.w;
      }
    }
  }

  float* m2k = m2low_g + k * 528;
  atomicAdd(&m2k[TRI(i1, j0)], c10);
  if (tj <= ti) {
    atomicAdd(&m2k[TRI(i0, j0)], c00);
    atomicAdd(&m2k[TRI(i1, j1)], c11);
  }
  if (tj == 0) {
    atomicAdd(&sums_g[k * DD + i0], sd0);
    atomicAdd(&sums_g[k * DD + i1], sd1);
  }
}

// finalize A (R8 verbatim, validated): one block per cluster.
__global__ __launch_bounds__(256) void finalizeA_kernel(
    const float* __restrict__ fill_g, const int* __restrict__ hist_g,
    const float* __restrict__ sums_g, const float* __restrict__ m2low_g,
    const float* __restrict__ ft, const float* __restrict__ mt,
    const float* __restrict__ ct, float* __restrict__ lossAcc) {
  __shared__ float meanS[DD];
  __shared__ float wred[4];
  const int t = threadIdx.x;
  const int k = blockIdx.x;

  const float inv = 1.0f / fmaxf((float)hist_g[k], 1.0f);
  if (t < DD) meanS[t] = sums_g[k * DD + t] * inv;
  __syncthreads();

  float acc = 0.f;
  if (t < DD) {
    const float d = meanS[t] - mt[k * DD + t];
    acc += d * d * (1.0f / (KK * DD));
  }
  if (t == 0) {
    const float f = fill_g[k] * (1.0f / (float)NR) - ft[k];
    acc += f * f * (1.0f / KK);
  }
  const float* m2k = m2low_g + k * 528;
  const float* ctk = ct + k * (DD * DD);
#pragma unroll
  for (int u = 0; u < 4; ++u) {
    const int e = t + 256 * u;
    const int i = e >> 5, j = e & 31;
    const int idx = (i >= j) ? TRI(i, j) : TRI(j, i);
    const float cov = m2k[idx] * inv - meanS[i] * meanS[j];
    const float d = cov - ctk[e];
    acc += d * d * (1.0f / (KK * DD * DD));
  }

  acc += __shfl_xor(acc, 32, 64);
  acc += __shfl_xor(acc, 16, 64);
  acc += __shfl_xor(acc, 8, 64);
  acc += __shfl_xor(acc, 4, 64);
  acc += __shfl_xor(acc, 2, 64);
  acc += __shfl_xor(acc, 1, 64);
  if ((t & 63) == 0) wred[t >> 6] = acc;
  __syncthreads();
  if (t == 0) atomicAdd(lossAcc, wred[0] + wred[1] + wred[2] + wred[3]);
}

__global__ void finalizeB_kernel(const float* __restrict__ lossAcc,
                                 float* __restrict__ out) {
  if (threadIdx.x == 0) out[0] = lossAcc[0];
}

extern "C" void kernel_launch(void* const* d_in, const int* in_sizes, int n_in,
                              void* d_out, int out_size, void* d_ws,
                              size_t ws_size, hipStream_t stream) {
  (void)in_sizes; (void)n_in; (void)out_size; (void)ws_size;
  const float* x = (const float*)d_in[0];
  const float* centers = (const float*)d_in[1];
  const float* ft = (const float*)d_in[2];
  const float* mt = (const float*)d_in[3];
  const float* ct = (const float*)d_in[4];
  float* out = (float*)d_out;

  float* ws = (float*)d_ws;
  float* fill_g = ws;                                   // 64
  float* lossAcc = ws + 64;                             // 1
  int* hist_g = (int*)(ws + 128);                       // 64
  int* segStart = (int*)(ws + 192);                     // 65
  int* cursor = (int*)(ws + 320);                       // 64
  unsigned char* wk = (unsigned char*)(ws + 384);       // GRIDW bytes
  int* wbase = (int*)(ws + 544);                        // GRIDW
  int* wcnt = (int*)(ws + 1184);                        // GRIDW
  float* m2low_g = ws + 1824;                           // 33792
  float* sums_g = ws + 35616;                           // 2048
  unsigned char* pred8 = (unsigned char*)(ws + 37664);  // N bytes
  float* xsort = ws + 70432;                            // N*D floats (16 MB)

  hipMemsetAsync(d_ws, 0, (size_t)37664 * sizeof(float), stream);

  phase1_kernel<<<NR / 256, 256, 0, stream>>>(x, centers, fill_g, hist_g,
                                              pred8);
  planner_kernel<<<1, 64, 0, stream>>>(hist_g, segStart, cursor, wk, wbase,
                                       wcnt);
  scatter_kernel<<<NR / 256, 256, 0, stream>>>(x, pred8, cursor, xsort);
  syrk_kernel<<<GRIDW, 256, 0, stream>>>(xsort, wk, wbase, wcnt, m2low_g,
                                         sums_g);
  finalizeA_kernel<<<KK, 256, 0, stream>>>(fill_g, hist_g, sums_g, m2low_g, ft,
                                           mt, ct, lossAcc);
  finalizeB_kernel<<<1, 64, 0, stream>>>(lossAcc, out);
}